// Round 15
// baseline (3172.067 us; speedup 1.0000x reference)
//
#include <hip/hip_runtime.h>
#include <cmath>

// B=32, S=512, T=64, IN=512, H=512, L=2, HC=4, OUT=512

typedef unsigned short ushort;
typedef unsigned int uint;
typedef __attribute__((ext_vector_type(8))) short bf16x8;
typedef __attribute__((ext_vector_type(4))) float f32x4;

__device__ __forceinline__ float sigmoidf_(float x) { return 1.f / (1.f + __expf(-x)); }
__device__ __forceinline__ float bf2f(ushort u) {
  union { uint i; float f; } x; x.i = ((uint)u) << 16; return x.f;
}
__device__ __forceinline__ ushort f2bf(float f) {
  union { float f; uint i; } x; x.f = f;
  return (ushort)((x.i + 0x7FFFu + ((x.i >> 16) & 1u)) >> 16);
}
__device__ __forceinline__ float wave_sum(float v) {
#pragma unroll
  for (int m = 1; m < 64; m <<= 1) v += __shfl_xor(v, m, 64);
  return v;
}
__device__ __forceinline__ float wave_max(float v) {
#pragma unroll
  for (int m = 1; m < 64; m <<= 1) v = fmaxf(v, __shfl_xor(v, m, 64));
  return v;
}

// ---------------- setup ------------------------------------------------------
__global__ void __launch_bounds__(256) k_init(const float* __restrict__ fh,
                                              ushort* h0b0, ushort* h1b0,
                                              float* c0, float* c1) {
  int i = blockIdx.x * 256 + threadIdx.x;  // 16384 = b*512+h
  h0b0[i] = f2bf(fh[i]);
  h1b0[i] = f2bf(fh[16384 + i]);
  c0[i] = 0.f; c1[i] = 0.f;
}

__global__ void __launch_bounds__(256) k_prep(const float* __restrict__ hid,
                                              ushort* __restrict__ hbf) {
  size_t i0 = ((size_t)blockIdx.x * 256 + threadIdx.x) * 8;
  float4 f0 = *(const float4*)&hid[i0];
  float4 f1 = *(const float4*)&hid[i0 + 4];
  uint4 o;
  o.x = (uint)f2bf(f0.x) | ((uint)f2bf(f0.y) << 16);
  o.y = (uint)f2bf(f0.z) | ((uint)f2bf(f0.w) << 16);
  o.z = (uint)f2bf(f1.x) | ((uint)f2bf(f1.y) << 16);
  o.w = (uint)f2bf(f1.z) | ((uint)f2bf(f1.w) << 16);
  *(uint4*)&hbf[i0] = o;
}

// inputs f32 [b][t][512] -> inb bf16 [(t*32+b)][512]
__global__ void __launch_bounds__(256) k_inprep(const float* __restrict__ inputs,
                                                ushort* __restrict__ inb) {
  size_t idx4 = ((size_t)blockIdx.x * 256 + threadIdx.x) * 4;
  int m = (int)(idx4 >> 9), k = (int)(idx4 & 511);
  int b = m & 31, tt = m >> 5;
  float4 v = *(const float4*)&inputs[((size_t)b * 64 + tt) * 512 + k];
  ushort4 o; o.x = f2bf(v.x); o.y = f2bf(v.y); o.z = f2bf(v.z); o.w = f2bf(v.w);
  *(ushort4*)&inb[(size_t)m * 512 + k] = o;
}

// pack weights bf16: dst[j][k] = k<split ? W1[j][k] : W2[j][k-split]
__global__ void __launch_bounds__(256) k_wcvt(const float* __restrict__ W1, int ld1,
                                              const float* __restrict__ W2, int ld2,
                                              int split, int K,
                                              ushort* __restrict__ dst) {
  size_t idx = ((size_t)blockIdx.x * 256 + threadIdx.x) * 4;
  int j = (int)(idx / K), k = (int)(idx % K);
  const float* src = (k < split) ? (W1 + (size_t)j * ld1 + k)
                                 : (W2 + (size_t)j * ld2 + (k - split));
  float4 v = *(const float4*)src;
  ushort4 o; o.x = f2bf(v.x); o.y = f2bf(v.y); o.z = f2bf(v.z); o.w = f2bf(v.w);
  *(ushort4*)&dst[idx] = o;
}

// ---------------- MFMA j-tile slice ------------------------------------------
__device__ __forceinline__ void mfma_slice(
    const ushort* __restrict__ W, int ldW, int jrow0, int jstride,
    const ushort* __restrict__ xA, int ldA, int xsplit,
    const ushort* __restrict__ xB, int ldB, int coff,
    int klo, int khi, float* __restrict__ redrow) {
  const int l = threadIdx.x & 63;
  const int r16 = l & 15, koff = (l >> 4) * 8;
  const int j = jrow0 + (r16 & 3) + (r16 >> 2) * jstride;
  const ushort* wrow = W + (size_t)j * ldW + koff;
  const ushort* a0A = xA + (size_t)r16 * ldA + koff;
  const ushort* a1A = xA + (size_t)(16 + r16) * ldA + koff;
  const ushort* a0B = xB + (size_t)r16 * ldB + koff;
  const ushort* a1B = xB + (size_t)(16 + r16) * ldB + koff;
  f32x4 acc0 = {0.f, 0.f, 0.f, 0.f}, acc1 = {0.f, 0.f, 0.f, 0.f};
#pragma unroll 4
  for (int k0 = klo; k0 < khi; k0 += 32) {
    bf16x8 av0, av1;
    if (k0 < xsplit) {
      av0 = *(const bf16x8*)(a0A + k0);
      av1 = *(const bf16x8*)(a1A + k0);
    } else {
      av0 = *(const bf16x8*)(a0B + (k0 - coff));
      av1 = *(const bf16x8*)(a1B + (k0 - coff));
    }
    bf16x8 wv = *(const bf16x8*)(wrow + k0);
    acc0 = __builtin_amdgcn_mfma_f32_16x16x32_bf16(av0, wv, acc0, 0, 0, 0);
    acc1 = __builtin_amdgcn_mfma_f32_16x16x32_bf16(av1, wv, acc1, 0, 0, 0);
  }
  const int brow = (l >> 4) << 2;
#pragma unroll
  for (int r = 0; r < 4; r++) {
    redrow[r16 * 33 + brow + r] = acc0[r];
    redrow[r16 * 33 + 16 + brow + r] = acc1[r];
  }
}

// hpb[r][n] = sum_k hbf[r][k] * Wa1c[n][k]   (bf16 MFMA, row-major out)
__global__ void __launch_bounds__(256) k_hidproj2(const ushort* __restrict__ Wa1c,
                                                  const ushort* __restrict__ hbf,
                                                  ushort* __restrict__ hpb) {
  __shared__ float red[4 * 528];
  int tid = threadIdx.x, w = tid >> 6;
  int j0 = blockIdx.x * 16;
  for (int mt = 0; mt < 4; mt++) {
    int m0 = (blockIdx.y * 4 + mt) * 32;
    mfma_slice(Wa1c, 512, j0, 4, hbf + (size_t)m0 * 512, 512, 1 << 30,
               hbf + (size_t)m0 * 512, 512, 0, w * 128, w * 128 + 128,
               red + w * 528);
    __syncthreads();
#pragma unroll
    for (int e = 0; e < 2; e++) {
      int idx = tid + e * 256;
      int j = idx >> 5, b = idx & 31;
      float v = 0.f;
#pragma unroll
      for (int ww = 0; ww < 4; ww++) v += red[ww * 528 + j * 33 + b];
      hpb[(size_t)(m0 + b) * 512 + j0 + j] = f2bf(v);
    }
    __syncthreads();
  }
}

// ---------------- static scores (setup; m=0; 4-way kd split) -----------------
__global__ void __launch_bounds__(512) k_scst(const ushort* __restrict__ hpb,
                                              const float* __restrict__ ba1,
                                              const float* __restrict__ Wa2,
                                              float4* __restrict__ scoresP4) {
  __shared__ float wa2s[512], ba1s[128];
  int bid = blockIdx.x, tid = threadIdx.x;
  int b = bid >> 2, kdq = bid & 3, kd0 = kdq << 7, s = tid;
  wa2s[tid] = Wa2[(tid >> 7) * 512 + kd0 + (tid & 127)];
  if (tid < 128) ba1s[tid] = ba1[kd0 + tid];
  __syncthreads();
  float a0 = 0.f, a1 = 0.f, a2 = 0.f, a3 = 0.f;
  const ushort* hpr = hpb + (size_t)(b * 512 + s) * 512 + kd0;
#pragma unroll
  for (int i8 = 0; i8 < 16; i8++) {
    bf16x8 hv8 = *(const bf16x8*)(hpr + i8 * 8);
#pragma unroll
    for (int e = 0; e < 8; e++) {
      int i = i8 * 8 + e;
      float a = fmaxf(bf2f(((ushort*)&hv8)[e]) + ba1s[i], 0.f);
      a0 += wa2s[i] * a;
      a1 += wa2s[128 + i] * a;
      a2 += wa2s[256 + i] * a;
      a3 += wa2s[384 + i] * a;
    }
  }
  scoresP4[((size_t)(kdq * 32 + b)) * 512 + s] = make_float4(a0, a1, a2, a3);
}

__global__ void __launch_bounds__(512) k_sum0(const float4* __restrict__ scoresP4,
                                              const float* __restrict__ ba2,
                                              float* __restrict__ scores0) {
  int idx = blockIdx.x * 512 + threadIdx.x;  // 16384 = b*512+s
  int b = idx >> 9, s = idx & 511;
  float a0 = ba2[0], a1 = ba2[1], a2 = ba2[2], a3 = ba2[3];
#pragma unroll
  for (int q = 0; q < 4; q++) {
    float4 p = scoresP4[((size_t)(q * 32 + b)) * 512 + s];
    a0 += p.x; a1 += p.y; a2 += p.z; a3 += p.w;
  }
  scores0[((size_t)b * 4 + 0) * 512 + s] = fmaxf(a0, 0.f);
  scores0[((size_t)b * 4 + 1) * 512 + s] = fmaxf(a1, 0.f);
  scores0[((size_t)b * 4 + 2) * 512 + s] = fmaxf(a2, 0.f);
  scores0[((size_t)b * 4 + 3) * 512 + s] = fmaxf(a3, 0.f);
}

// m0[b][k], statZ[b][k], P0[b][k][s] = s>=len ? exp(scores0-m0) : 0
__global__ void __launch_bounds__(512) k_stat0(const float* __restrict__ scores0,
                                               const int* __restrict__ lengths,
                                               float* __restrict__ m0v,
                                               float* __restrict__ statZ,
                                               float* __restrict__ P0) {
  __shared__ float st[32], st2[32];
  int b = blockIdx.x, tid = threadIdx.x, lane = tid & 63, w = tid >> 6;
  int s = tid, len = lengths[b];
  bool stat = s >= len;
  float v[4], m0[4];
#pragma unroll
  for (int k = 0; k < 4; k++) v[k] = scores0[((size_t)b * 4 + k) * 512 + s];
#pragma unroll
  for (int k = 0; k < 4; k++) {
    float mk = wave_max(stat ? v[k] : -1e30f);
    if (lane == 0) st[w * 4 + k] = mk;
  }
  __syncthreads();
#pragma unroll
  for (int k = 0; k < 4; k++) {
    float m = st[k];
#pragma unroll
    for (int w2 = 1; w2 < 8; w2++) m = fmaxf(m, st[w2 * 4 + k]);
    m0[k] = m;
  }
  float e[4];
#pragma unroll
  for (int k = 0; k < 4; k++) {
    e[k] = stat ? __expf(v[k] - m0[k]) : 0.f;
    float sk = wave_sum(e[k]);
    if (lane == 0) st2[w * 4 + k] = sk;
  }
  __syncthreads();
#pragma unroll
  for (int k = 0; k < 4; k++) {
    P0[((size_t)b * 4 + k) * 512 + s] = e[k];
  }
  if (tid == 0) {
#pragma unroll
    for (int k = 0; k < 4; k++) {
      float z = 0.f;
#pragma unroll
      for (int w2 = 0; w2 < 8; w2++) z += st2[w2 * 4 + k];
      m0v[b * 4 + k] = m0[k];
      statZ[b * 4 + k] = z;
    }
  }
}

// staticvec[b][k][h] = sum_s P0[b][k][s]*hbf[b][s][h]
__global__ void __launch_bounds__(512) k_statvec(const float* __restrict__ P0,
                                                 const ushort* __restrict__ hbf,
                                                 const int* __restrict__ lengths,
                                                 float* __restrict__ statvec) {
  __shared__ float P[4 * 512];
  __shared__ float red2[8 * 256];
  int bid = blockIdx.x, tid = threadIdx.x;
  int b = bid >> 3, hs = bid & 7;
#pragma unroll
  for (int k = 0; k < 4; k++) P[k * 512 + tid] = P0[((size_t)b * 4 + k) * 512 + tid];
  __syncthreads();
  int h = tid & 63, w8 = tid >> 6;
  int len = lengths[b];
  float a0 = 0.f, a1 = 0.f, a2 = 0.f, a3 = 0.f;
  for (int si = len + ((w8 - len) & 7); si < 512; si += 8) {
    float hv = bf2f(hbf[((size_t)(b * 512 + si) * 512) + (hs << 6) + h]);
    a0 += P[si] * hv;
    a1 += P[512 + si] * hv;
    a2 += P[1024 + si] * hv;
    a3 += P[1536 + si] * hv;
  }
  red2[(w8 << 8) + h] = a0;
  red2[(w8 << 8) + 64 + h] = a1;
  red2[(w8 << 8) + 128 + h] = a2;
  red2[(w8 << 8) + 192 + h] = a3;
  __syncthreads();
  if (tid < 256) {
    int k = tid >> 6, hh = tid & 63;
    float acc = 0.f;
#pragma unroll
    for (int c = 0; c < 8; c++) acc += red2[(c << 8) + (k << 6) + hh];
    statvec[((size_t)b * 4 + k) * 512 + (hs << 6) + hh] = acc;
  }
}

// ---------------- setup GEMM: gi0[m][j] = inb[m] . Wih0[j][0:512] ------------
__global__ void __launch_bounds__(256) k_gin0(const ushort* __restrict__ Wg0b,
                                              const ushort* __restrict__ inb,
                                              float* __restrict__ gi0) {
  __shared__ float red[4 * 528];
  int tid = threadIdx.x, w = tid >> 6;
  int j0 = blockIdx.x * 16;
  for (int mt = 0; mt < 4; mt++) {
    int m0 = (blockIdx.y * 4 + mt) * 32;
    mfma_slice(Wg0b, 3072, j0, 4, inb + (size_t)m0 * 512, 512, 1 << 30,
               inb + (size_t)m0 * 512, 512, 0, w * 128, w * 128 + 128,
               red + w * 528);
    __syncthreads();
#pragma unroll
    for (int e = 0; e < 2; e++) {
      int idx = tid + e * 256;
      int j = idx >> 5, b = idx & 31;
      float v = 0.f;
#pragma unroll
      for (int ww = 0; ww < 4; ww++) v += red[ww * 528 + j * 33 + b];
      gi0[(size_t)(m0 + b) * 2048 + j0 + j] = v;
    }
    __syncthreads();
  }
}

// ---------------- K1: o1(t-1) || [q+scores](t) -------------------------------
__global__ void __launch_bounds__(512) k_scq(
    const ushort* __restrict__ Wq, const ushort* __restrict__ Wo1,
    const ushort* __restrict__ h1cur, const ushort* __restrict__ xb,
    const float* __restrict__ bo1, ushort* __restrict__ o1bf,
    const ushort* __restrict__ hpb, const float* __restrict__ ba1,
    const float* __restrict__ Wa2, const int* __restrict__ lengths,
    float4* __restrict__ scoresP4, int t) {
  __shared__ float red[8 * 528];
  __shared__ float qs[128], wa2s[512], ba1s[128];
  int bid = blockIdx.x, tid = threadIdx.x, w = tid >> 6, lane = tid & 63;
  if (bid < 32) {
    if (t < 1) return;
    mfma_slice(Wo1, 2560, bid * 16, 4, h1cur, 512, 512, xb, 2048, 512,
               w * 320, w * 320 + 320, red + w * 528);
    __syncthreads();
    int j = tid & 15, b = tid >> 4;
    float v = 0.f;
#pragma unroll
    for (int ww = 0; ww < 8; ww++) v += red[ww * 528 + j * 33 + b];
    int jj = bid * 16 + j;
    o1bf[b * 512 + jj] = f2bf(fmaxf(v + bo1[jj], 0.f));
  } else {
    if (t >= 64) return;
    int r = bid - 32;  // 0..127
    int b = r >> 2, kdq = r & 3, kd0 = kdq << 7;
    wa2s[tid] = Wa2[(tid >> 7) * 512 + kd0 + (tid & 127)];
    if (tid < 128) ba1s[tid] = ba1[kd0 + tid];
    // q phase: wave w computes q rows kd0 + w*16 .. +16
    {
      bf16x8 hv8 = *(const bf16x8*)(h1cur + b * 512 + lane * 8);
      float hf[8];
#pragma unroll
      for (int e2 = 0; e2 < 8; e2++) hf[e2] = bf2f(((ushort*)&hv8)[e2]);
#pragma unroll
      for (int rr = 0; rr < 16; rr++) {
        int row = kd0 + w * 16 + rr;
        bf16x8 wv8 = *(const bf16x8*)(Wq + (size_t)row * 512 + lane * 8);
        float acc = 0.f;
#pragma unroll
        for (int e2 = 0; e2 < 8; e2++) acc += hf[e2] * bf2f(((ushort*)&wv8)[e2]);
        acc = wave_sum(acc);
        if (lane == 0) qs[w * 16 + rr] = acc;
      }
    }
    __syncthreads();
    int s = tid, len = lengths[b];
    if ((tid & ~63) >= len) return;  // whole wave static -> skip
    float m = (s < len) ? 1.f : 0.f;
    float a0 = 0.f, a1 = 0.f, a2 = 0.f, a3 = 0.f;
    const ushort* hpr = hpb + (size_t)(b * 512 + s) * 512 + kd0;
#pragma unroll
    for (int i8 = 0; i8 < 16; i8++) {
      bf16x8 hv8 = *(const bf16x8*)(hpr + i8 * 8);
#pragma unroll
      for (int e = 0; e < 8; e++) {
        int i = i8 * 8 + e;
        float a = fmaxf(bf2f(((ushort*)&hv8)[e]) + ba1s[i] + m * qs[i], 0.f);
        a0 += wa2s[i] * a;
        a1 += wa2s[128 + i] * a;
        a2 += wa2s[256 + i] * a;
        a3 += wa2s[384 + i] * a;
      }
    }
    scoresP4[((size_t)(kdq * 32 + b)) * 512 + s] = make_float4(a0, a1, a2, a3);
  }
}

// ---------------- K2: out(t-1) || ctx(t) -------------------------------------
__global__ void __launch_bounds__(512) k_ctxout(
    const float4* __restrict__ scoresP4, const float* __restrict__ ba2,
    const int* __restrict__ lengths, const ushort* __restrict__ hbf,
    const float* __restrict__ m0v, const float* __restrict__ statZ,
    const float* __restrict__ statvec, ushort* __restrict__ xb,
    const ushort* __restrict__ Wo2, const ushort* __restrict__ o1bf,
    const float* __restrict__ bo2, float* __restrict__ outp, int t) {
  __shared__ float red[8 * 528];
  __shared__ float P[4 * 512];
  __shared__ float red2[8 * 256];
  __shared__ float st[32], st2[32];
  int bid = blockIdx.x, tid = threadIdx.x;
  if (bid < 32) {
    if (t < 1) return;
    int w = tid >> 6;
    mfma_slice(Wo2, 512, bid * 16, 4, o1bf, 512, 1 << 30, o1bf, 512, 0,
               w * 64, w * 64 + 64, red + w * 528);
    __syncthreads();
    int j = tid & 15, b = tid >> 4;
    float v = 0.f;
#pragma unroll
    for (int ww = 0; ww < 8; ww++) v += red[ww * 528 + j * 33 + b];
    int jj = bid * 16 + j;
    outp[((size_t)b * 64 + (t - 1)) * 512 + jj] = tanhf(v + bo2[jj]);
  } else {
    if (t >= 64) return;
    int r = bid - 32;
    int b = r >> 3, hs = r & 7;
    int lane = tid & 63, w = tid >> 6;
    int s = tid, len = lengths[b];
    bool act = s < len;
    float v[4];
    {
      float a0 = ba2[0], a1 = ba2[1], a2 = ba2[2], a3 = ba2[3];
      if (act) {
#pragma unroll
        for (int q = 0; q < 4; q++) {
          float4 p = scoresP4[((size_t)(q * 32 + b)) * 512 + s];
          a0 += p.x; a1 += p.y; a2 += p.z; a3 += p.w;
        }
        v[0] = fmaxf(a0, 0.f); v[1] = fmaxf(a1, 0.f);
        v[2] = fmaxf(a2, 0.f); v[3] = fmaxf(a3, 0.f);
      } else {
        v[0] = v[1] = v[2] = v[3] = -1e30f;
      }
    }
    float M[4];
#pragma unroll
    for (int k = 0; k < 4; k++) {
      float mk = wave_max(v[k]);
      if (lane == 0) st[w * 4 + k] = mk;
    }
    __syncthreads();
#pragma unroll
    for (int k = 0; k < 4; k++) {
      float m = st[k];
#pragma unroll
      for (int w2 = 1; w2 < 8; w2++) m = fmaxf(m, st[w2 * 4 + k]);
      M[k] = fmaxf(m, m0v[b * 4 + k]);
    }
    float e[4];
#pragma unroll
    for (int k = 0; k < 4; k++) {
      e[k] = act ? __expf(v[k] - M[k]) : 0.f;
      float sk = wave_sum(e[k]);
      if (lane == 0) st2[w * 4 + k] = sk;
    }
    __syncthreads();
    float sc[4];
#pragma unroll
    for (int k = 0; k < 4; k++) {
      float dynZ = 0.f;
#pragma unroll
      for (int w2 = 0; w2 < 8; w2++) dynZ += st2[w2 * 4 + k];
      float scB = __expf(m0v[b * 4 + k] - M[k]);
      float Z = dynZ + scB * statZ[b * 4 + k];
      float invZ = 1.f / Z;
      P[k * 512 + s] = e[k] * invZ;
      sc[k] = scB * invZ;
    }
    __syncthreads();
    int h = tid & 63, w8 = tid >> 6;
    float a0 = 0.f, a1 = 0.f, a2 = 0.f, a3 = 0.f;
    const ushort* hb0 = hbf + ((size_t)b * 512) * 512 + (hs << 6) + h;
    int si = w8;
    for (; si + 24 < len; si += 32) {
      float h0v = bf2f(hb0[(size_t)si * 512]);
      float h1v = bf2f(hb0[(size_t)(si + 8) * 512]);
      float h2v = bf2f(hb0[(size_t)(si + 16) * 512]);
      float h3v = bf2f(hb0[(size_t)(si + 24) * 512]);
      a0 += P[si] * h0v + P[si + 8] * h1v + P[si + 16] * h2v + P[si + 24] * h3v;
      a1 += P[512 + si] * h0v + P[512 + si + 8] * h1v + P[512 + si + 16] * h2v +
            P[512 + si + 24] * h3v;
      a2 += P[1024 + si] * h0v + P[1024 + si + 8] * h1v + P[1024 + si + 16] * h2v +
            P[1024 + si + 24] * h3v;
      a3 += P[1536 + si] * h0v + P[1536 + si + 8] * h1v + P[1536 + si + 16] * h2v +
            P[1536 + si + 24] * h3v;
    }
    for (; si < len; si += 8) {
      float hv = bf2f(hb0[(size_t)si * 512]);
      a0 += P[si] * hv;
      a1 += P[512 + si] * hv;
      a2 += P[1024 + si] * hv;
      a3 += P[1536 + si] * hv;
    }
    red2[(w8 << 8) + h] = a0;
    red2[(w8 << 8) + 64 + h] = a1;
    red2[(w8 << 8) + 128 + h] = a2;
    red2[(w8 << 8) + 192 + h] = a3;
    __syncthreads();
    if (tid < 256) {
      int k = tid >> 6, hh = tid & 63;
      float acc = 0.f;
#pragma unroll
      for (int c = 0; c < 8; c++) acc += red2[(c << 8) + (k << 6) + hh];
      acc += sc[k] * statvec[((size_t)b * 4 + k) * 512 + (hs << 6) + hh];
      xb[b * 2048 + (k << 9) + (hs << 6) + hh] = f2bf(acc);
    }
  }
}

// ---------------- K3: LSTM cell0 (512 thr, 8-way k-split, K=2560) ------------
__global__ void __launch_bounds__(512) k_cell0(
    const ushort* __restrict__ Wg0b, const ushort* __restrict__ xb,
    const ushort* __restrict__ h0cur, const float* __restrict__ gi0,
    const float* __restrict__ bih, const float* __restrict__ bhh,
    float* __restrict__ cst, ushort* __restrict__ hnew, int t) {
  __shared__ float red[8 * 528];
  int bid = blockIdx.x, tid = threadIdx.x, w = tid >> 6;
  mfma_slice(Wg0b + 512, 3072, bid * 4, 512, xb, 2048, 2048, h0cur, 512, 2048,
             w * 320, w * 320 + 320, red + w * 528);
  __syncthreads();
  if (tid < 128) {
    int b = tid & 31, dh = tid >> 5;
    int h = bid * 4 + dh;
    float G[4];
#pragma unroll
    for (int g = 0; g < 4; g++) {
      float v = bih[g * 512 + h] + bhh[g * 512 + h] +
                gi0[(size_t)(t * 32 + b) * 2048 + g * 512 + h];
#pragma unroll
      for (int ww = 0; ww < 8; ww++) v += red[ww * 528 + (g * 4 + dh) * 33 + b];
      G[g] = v;
    }
    float i_ = sigmoidf_(G[0]), f_ = sigmoidf_(G[1]);
    float gg = tanhf(G[2]), o_ = sigmoidf_(G[3]);
    float cn = f_ * cst[b * 512 + h] + i_ * gg;
    cst[b * 512 + h] = cn;
    hnew[b * 512 + h] = f2bf(o_ * tanhf(cn));
  }
}

// ---------------- K4: LSTM cell1 (512 thr, 8-way k-split, K=1024) ------------
__global__ void __launch_bounds__(512) k_cell1(
    const ushort* __restrict__ Wg1b, const ushort* __restrict__ h0new,
    const ushort* __restrict__ h1cur, const float* __restrict__ bih,
    const float* __restrict__ bhh, float* __restrict__ cst,
    ushort* __restrict__ hnew) {
  __shared__ float red[8 * 528];
  int bid = blockIdx.x, tid = threadIdx.x, w = tid >> 6;
  mfma_slice(Wg1b, 1024, bid * 4, 512, h0new, 512, 512, h1cur, 512, 512,
             w * 128, w * 128 + 128, red + w * 528);
  __syncthreads();
  if (tid < 128) {
    int b = tid & 31, dh = tid >> 5;
    int h = bid * 4 + dh;
    float G[4];
#pragma unroll
    for (int g = 0; g < 4; g++) {
      float v = bih[g * 512 + h] + bhh[g * 512 + h];
#pragma unroll
      for (int ww = 0; ww < 8; ww++) v += red[ww * 528 + (g * 4 + dh) * 33 + b];
      G[g] = v;
    }
    float i_ = sigmoidf_(G[0]), f_ = sigmoidf_(G[1]);
    float gg = tanhf(G[2]), o_ = sigmoidf_(G[3]);
    float cn = f_ * cst[b * 512 + h] + i_ * gg;
    cst[b * 512 + h] = cn;
    hnew[b * 512 + h] = f2bf(o_ * tanhf(cn));
  }
}

// ---------------- host -------------------------------------------------------
extern "C" void kernel_launch(void* const* d_in, const int* in_sizes, int n_in,
                              void* d_out, int out_size, void* d_ws, size_t ws_size,
                              hipStream_t stream) {
  const float* inputs  = (const float*)d_in[0];
  const int*   lengths = (const int*)d_in[1];
  const float* fh      = (const float*)d_in[2];
  const float* hiddens = (const float*)d_in[3];
  const float* Wa1  = (const float*)d_in[6];
  const float* ba1  = (const float*)d_in[7];
  const float* Wa2  = (const float*)d_in[8];
  const float* ba2  = (const float*)d_in[9];
  const float* Wih0 = (const float*)d_in[10];
  const float* Whh0 = (const float*)d_in[11];
  const float* bih0 = (const float*)d_in[12];
  const float* bhh0 = (const float*)d_in[13];
  const float* Wih1 = (const float*)d_in[14];
  const float* Whh1 = (const float*)d_in[15];
  const float* bih1 = (const float*)d_in[16];
  const float* bhh1 = (const float*)d_in[17];
  const float* Wo1  = (const float*)d_in[18];
  const float* bo1  = (const float*)d_in[19];
  const float* Wo2  = (const float*)d_in[20];
  const float* bo2  = (const float*)d_in[21];
  float* outp = (float*)d_out;

  char* p = (char*)d_ws;
  ushort* hpb = (ushort*)p; p += (size_t)32 * 512 * 512 * 2;
  ushort* hbf = (ushort*)p; p += (size_t)32 * 512 * 512 * 2;
  float4* scoresP4 = (float4*)p; p += (size_t)4 * 32 * 512 * 16;
  float* scores0 = (float*)p; p += (size_t)32 * 4 * 512 * 4;
  float* P0      = (float*)p; p += (size_t)32 * 4 * 512 * 4;
  float* statvec = (float*)p; p += (size_t)32 * 4 * 512 * 4;
  float* m0v     = (float*)p; p += 128 * sizeof(float);
  float* statZ   = (float*)p; p += 128 * sizeof(float);
  ushort* xb     = (ushort*)p; p += (size_t)32 * 2048 * 2;
  ushort* h0b    = (ushort*)p; p += (size_t)2 * 32 * 512 * 2;
  ushort* h1b    = (ushort*)p; p += (size_t)2 * 32 * 512 * 2;
  ushort* o1bf   = (ushort*)p; p += (size_t)32 * 512 * 2;
  float* c0      = (float*)p; p += (size_t)32 * 512 * 4;
  float* c1      = (float*)p; p += (size_t)32 * 512 * 4;
  ushort* Wg0b   = (ushort*)p; p += (size_t)2048 * 3072 * 2;
  ushort* Wg1b   = (ushort*)p; p += (size_t)2048 * 1024 * 2;
  ushort* Wo1b   = (ushort*)p; p += (size_t)512 * 2560 * 2;
  ushort* Wo2b   = (ushort*)p; p += (size_t)512 * 512 * 2;
  ushort* Wqb    = (ushort*)p; p += (size_t)512 * 512 * 2;
  ushort* Wa1c   = (ushort*)p; p += (size_t)512 * 512 * 2;
  ushort* inb    = (ushort*)p; p += (size_t)2048 * 512 * 2;
  float* gi0     = (float*)p; p += (size_t)2048 * 2048 * 4;

  k_init<<<64, 256, 0, stream>>>(fh, h0b, h1b, c0, c1);
  k_prep<<<4096, 256, 0, stream>>>(hiddens, hbf);
  k_inprep<<<1024, 256, 0, stream>>>(inputs, inb);
  k_wcvt<<<6144, 256, 0, stream>>>(Wih0, 2560, Whh0, 512, 2560, 3072, Wg0b);
  k_wcvt<<<2048, 256, 0, stream>>>(Wih1, 512, Whh1, 512, 512, 1024, Wg1b);
  k_wcvt<<<1280, 256, 0, stream>>>(Wo1, 2560, Wo1, 2560, 2560, 2560, Wo1b);
  k_wcvt<<<256, 256, 0, stream>>>(Wo2, 512, Wo2, 512, 512, 512, Wo2b);
  k_wcvt<<<256, 256, 0, stream>>>(Wa1, 1024, Wa1, 1024, 512, 512, Wqb);
  k_wcvt<<<256, 256, 0, stream>>>(Wa1 + 512, 1024, Wa1 + 512, 1024, 1 << 30, 512, Wa1c);
  k_hidproj2<<<dim3(32, 128), 256, 0, stream>>>(Wa1c, hbf, hpb);
  k_gin0<<<dim3(128, 16), 256, 0, stream>>>(Wg0b, inb, gi0);
  k_scst<<<128, 512, 0, stream>>>(hpb, ba1, Wa2, scoresP4);
  k_sum0<<<32, 512, 0, stream>>>(scoresP4, ba2, scores0);
  k_stat0<<<32, 512, 0, stream>>>(scores0, lengths, m0v, statZ, P0);
  k_statvec<<<256, 512, 0, stream>>>(P0, hbf, lengths, statvec);

  for (int t = 0; t <= 64; t++) {
    const ushort* h1cur = h1b + (size_t)(t & 1) * 16384;
    const ushort* h0cur = h0b + (size_t)(t & 1) * 16384;
    ushort* h0nxt = h0b + (size_t)((t + 1) & 1) * 16384;
    ushort* h1nxt = h1b + (size_t)((t + 1) & 1) * 16384;
    k_scq<<<160, 512, 0, stream>>>(Wqb, Wo1b, h1cur, xb, bo1, o1bf, hpb, ba1,
                                   Wa2, lengths, scoresP4, t);
    k_ctxout<<<288, 512, 0, stream>>>(scoresP4, ba2, lengths, hbf, m0v, statZ,
                                      statvec, xb, Wo2b, o1bf, bo2, outp, t);
    if (t < 64) {
      k_cell0<<<128, 512, 0, stream>>>(Wg0b, xb, h0cur, gi0, bih0, bhh0, c0,
                                       h0nxt, t);
      k_cell1<<<128, 512, 0, stream>>>(Wg1b, h0nxt, h1cur, bih1, bhh1, c1, h1nxt);
    }
  }
}

// Round 16
// 2912.074 us; speedup vs baseline: 1.0893x; 1.0893x over previous
//
#include <hip/hip_runtime.h>
#include <cmath>

// B=32, S=512, T=64, IN=512, H=512, L=2, HC=4, OUT=512
// Locked configuration == Round 13 (best measured: 2913 us).

typedef unsigned short ushort;
typedef unsigned int uint;
typedef __attribute__((ext_vector_type(8))) short bf16x8;
typedef __attribute__((ext_vector_type(4))) float f32x4;

__device__ __forceinline__ float sigmoidf_(float x) { return 1.f / (1.f + __expf(-x)); }
__device__ __forceinline__ float bf2f(ushort u) {
  union { uint i; float f; } x; x.i = ((uint)u) << 16; return x.f;
}
__device__ __forceinline__ ushort f2bf(float f) {
  union { float f; uint i; } x; x.f = f;
  return (ushort)((x.i + 0x7FFFu + ((x.i >> 16) & 1u)) >> 16);
}
__device__ __forceinline__ float wave_sum(float v) {
#pragma unroll
  for (int m = 1; m < 64; m <<= 1) v += __shfl_xor(v, m, 64);
  return v;
}
__device__ __forceinline__ float wave_max(float v) {
#pragma unroll
  for (int m = 1; m < 64; m <<= 1) v = fmaxf(v, __shfl_xor(v, m, 64));
  return v;
}

// ---------------- setup ------------------------------------------------------
__global__ void __launch_bounds__(256) k_init(const float* __restrict__ fh,
                                              ushort* h0b0, ushort* h1b0,
                                              float* c0, float* c1) {
  int i = blockIdx.x * 256 + threadIdx.x;  // 16384 = b*512+h
  h0b0[i] = f2bf(fh[i]);
  h1b0[i] = f2bf(fh[16384 + i]);
  c0[i] = 0.f; c1[i] = 0.f;
}

__global__ void __launch_bounds__(256) k_prep(const float* __restrict__ hid,
                                              ushort* __restrict__ hbf) {
  size_t i0 = ((size_t)blockIdx.x * 256 + threadIdx.x) * 8;
  float4 f0 = *(const float4*)&hid[i0];
  float4 f1 = *(const float4*)&hid[i0 + 4];
  uint4 o;
  o.x = (uint)f2bf(f0.x) | ((uint)f2bf(f0.y) << 16);
  o.y = (uint)f2bf(f0.z) | ((uint)f2bf(f0.w) << 16);
  o.z = (uint)f2bf(f1.x) | ((uint)f2bf(f1.y) << 16);
  o.w = (uint)f2bf(f1.z) | ((uint)f2bf(f1.w) << 16);
  *(uint4*)&hbf[i0] = o;
}

// inputs f32 [b][t][512] -> inb bf16 [(t*32+b)][512]
__global__ void __launch_bounds__(256) k_inprep(const float* __restrict__ inputs,
                                                ushort* __restrict__ inb) {
  size_t idx4 = ((size_t)blockIdx.x * 256 + threadIdx.x) * 4;
  int m = (int)(idx4 >> 9), k = (int)(idx4 & 511);
  int b = m & 31, tt = m >> 5;
  float4 v = *(const float4*)&inputs[((size_t)b * 64 + tt) * 512 + k];
  ushort4 o; o.x = f2bf(v.x); o.y = f2bf(v.y); o.z = f2bf(v.z); o.w = f2bf(v.w);
  *(ushort4*)&inb[(size_t)m * 512 + k] = o;
}

// pack weights bf16: dst[j][k] = k<split ? W1[j][k] : W2[j][k-split]
__global__ void __launch_bounds__(256) k_wcvt(const float* __restrict__ W1, int ld1,
                                              const float* __restrict__ W2, int ld2,
                                              int split, int K,
                                              ushort* __restrict__ dst) {
  size_t idx = ((size_t)blockIdx.x * 256 + threadIdx.x) * 4;
  int j = (int)(idx / K), k = (int)(idx % K);
  const float* src = (k < split) ? (W1 + (size_t)j * ld1 + k)
                                 : (W2 + (size_t)j * ld2 + (k - split));
  float4 v = *(const float4*)src;
  ushort4 o; o.x = f2bf(v.x); o.y = f2bf(v.y); o.z = f2bf(v.z); o.w = f2bf(v.w);
  *(ushort4*)&dst[idx] = o;
}

// ---------------- MFMA j-tile slice ------------------------------------------
__device__ __forceinline__ void mfma_slice(
    const ushort* __restrict__ W, int ldW, int jrow0, int jstride,
    const ushort* __restrict__ xA, int ldA, int xsplit,
    const ushort* __restrict__ xB, int ldB, int coff,
    int klo, int khi, float* __restrict__ redrow) {
  const int l = threadIdx.x & 63;
  const int r16 = l & 15, koff = (l >> 4) * 8;
  const int j = jrow0 + (r16 & 3) + (r16 >> 2) * jstride;
  const ushort* wrow = W + (size_t)j * ldW + koff;
  const ushort* a0A = xA + (size_t)r16 * ldA + koff;
  const ushort* a1A = xA + (size_t)(16 + r16) * ldA + koff;
  const ushort* a0B = xB + (size_t)r16 * ldB + koff;
  const ushort* a1B = xB + (size_t)(16 + r16) * ldB + koff;
  f32x4 acc0 = {0.f, 0.f, 0.f, 0.f}, acc1 = {0.f, 0.f, 0.f, 0.f};
#pragma unroll 4
  for (int k0 = klo; k0 < khi; k0 += 32) {
    bf16x8 av0, av1;
    if (k0 < xsplit) {
      av0 = *(const bf16x8*)(a0A + k0);
      av1 = *(const bf16x8*)(a1A + k0);
    } else {
      av0 = *(const bf16x8*)(a0B + (k0 - coff));
      av1 = *(const bf16x8*)(a1B + (k0 - coff));
    }
    bf16x8 wv = *(const bf16x8*)(wrow + k0);
    acc0 = __builtin_amdgcn_mfma_f32_16x16x32_bf16(av0, wv, acc0, 0, 0, 0);
    acc1 = __builtin_amdgcn_mfma_f32_16x16x32_bf16(av1, wv, acc1, 0, 0, 0);
  }
  const int brow = (l >> 4) << 2;
#pragma unroll
  for (int r = 0; r < 4; r++) {
    redrow[r16 * 33 + brow + r] = acc0[r];
    redrow[r16 * 33 + 16 + brow + r] = acc1[r];
  }
}

// hpb[r][n] = sum_k hbf[r][k] * Wa1c[n][k]   (bf16 MFMA, row-major out)
__global__ void __launch_bounds__(256) k_hidproj2(const ushort* __restrict__ Wa1c,
                                                  const ushort* __restrict__ hbf,
                                                  ushort* __restrict__ hpb) {
  __shared__ float red[4 * 528];
  int tid = threadIdx.x, w = tid >> 6;
  int j0 = blockIdx.x * 16;
  for (int mt = 0; mt < 4; mt++) {
    int m0 = (blockIdx.y * 4 + mt) * 32;
    mfma_slice(Wa1c, 512, j0, 4, hbf + (size_t)m0 * 512, 512, 1 << 30,
               hbf + (size_t)m0 * 512, 512, 0, w * 128, w * 128 + 128,
               red + w * 528);
    __syncthreads();
#pragma unroll
    for (int e = 0; e < 2; e++) {
      int idx = tid + e * 256;
      int j = idx >> 5, b = idx & 31;
      float v = 0.f;
#pragma unroll
      for (int ww = 0; ww < 4; ww++) v += red[ww * 528 + j * 33 + b];
      hpb[(size_t)(m0 + b) * 512 + j0 + j] = f2bf(v);
    }
    __syncthreads();
  }
}

// ---------------- static scores (setup; m=0; 8-way kd split) -----------------
__global__ void __launch_bounds__(512) k_scst(const ushort* __restrict__ hpb,
                                              const float* __restrict__ ba1,
                                              const float* __restrict__ Wa2,
                                              float4* __restrict__ scoresP4) {
  __shared__ float wa2s[256], ba1s[64];
  int bid = blockIdx.x, tid = threadIdx.x;
  int b = bid >> 3, kdq = bid & 7, kd0 = kdq << 6, s = tid;
  if (tid < 256) wa2s[tid] = Wa2[(tid >> 6) * 512 + kd0 + (tid & 63)];
  else if (tid < 320) ba1s[tid - 256] = ba1[kd0 + (tid - 256)];
  __syncthreads();
  float a0 = 0.f, a1 = 0.f, a2 = 0.f, a3 = 0.f;
  const ushort* hpr = hpb + (size_t)(b * 512 + s) * 512 + kd0;
#pragma unroll
  for (int i8 = 0; i8 < 8; i8++) {
    bf16x8 hv8 = *(const bf16x8*)(hpr + i8 * 8);
#pragma unroll
    for (int e = 0; e < 8; e++) {
      int i = i8 * 8 + e;
      float a = fmaxf(bf2f(((ushort*)&hv8)[e]) + ba1s[i], 0.f);
      a0 += wa2s[i] * a;
      a1 += wa2s[64 + i] * a;
      a2 += wa2s[128 + i] * a;
      a3 += wa2s[192 + i] * a;
    }
  }
  scoresP4[((size_t)(kdq * 32 + b)) * 512 + s] = make_float4(a0, a1, a2, a3);
}

__global__ void __launch_bounds__(512) k_sum0(const float4* __restrict__ scoresP4,
                                              const float* __restrict__ ba2,
                                              float* __restrict__ scores0) {
  int idx = blockIdx.x * 512 + threadIdx.x;  // 16384 = b*512+s
  int b = idx >> 9, s = idx & 511;
  float a0 = ba2[0], a1 = ba2[1], a2 = ba2[2], a3 = ba2[3];
#pragma unroll
  for (int q = 0; q < 8; q++) {
    float4 p = scoresP4[((size_t)(q * 32 + b)) * 512 + s];
    a0 += p.x; a1 += p.y; a2 += p.z; a3 += p.w;
  }
  scores0[((size_t)b * 4 + 0) * 512 + s] = fmaxf(a0, 0.f);
  scores0[((size_t)b * 4 + 1) * 512 + s] = fmaxf(a1, 0.f);
  scores0[((size_t)b * 4 + 2) * 512 + s] = fmaxf(a2, 0.f);
  scores0[((size_t)b * 4 + 3) * 512 + s] = fmaxf(a3, 0.f);
}

// m0[b][k], statZ[b][k], P0[b][k][s] = s>=len ? exp(scores0-m0) : 0
__global__ void __launch_bounds__(512) k_stat0(const float* __restrict__ scores0,
                                               const int* __restrict__ lengths,
                                               float* __restrict__ m0v,
                                               float* __restrict__ statZ,
                                               float* __restrict__ P0) {
  __shared__ float st[32], st2[32];
  int b = blockIdx.x, tid = threadIdx.x, lane = tid & 63, w = tid >> 6;
  int s = tid, len = lengths[b];
  bool stat = s >= len;
  float v[4], m0[4];
#pragma unroll
  for (int k = 0; k < 4; k++) v[k] = scores0[((size_t)b * 4 + k) * 512 + s];
#pragma unroll
  for (int k = 0; k < 4; k++) {
    float mk = wave_max(stat ? v[k] : -1e30f);
    if (lane == 0) st[w * 4 + k] = mk;
  }
  __syncthreads();
#pragma unroll
  for (int k = 0; k < 4; k++) {
    float m = st[k];
#pragma unroll
    for (int w2 = 1; w2 < 8; w2++) m = fmaxf(m, st[w2 * 4 + k]);
    m0[k] = m;
  }
  float e[4];
#pragma unroll
  for (int k = 0; k < 4; k++) {
    e[k] = stat ? __expf(v[k] - m0[k]) : 0.f;
    float sk = wave_sum(e[k]);
    if (lane == 0) st2[w * 4 + k] = sk;
  }
  __syncthreads();
#pragma unroll
  for (int k = 0; k < 4; k++) {
    P0[((size_t)b * 4 + k) * 512 + s] = e[k];
  }
  if (tid == 0) {
#pragma unroll
    for (int k = 0; k < 4; k++) {
      float z = 0.f;
#pragma unroll
      for (int w2 = 0; w2 < 8; w2++) z += st2[w2 * 4 + k];
      m0v[b * 4 + k] = m0[k];
      statZ[b * 4 + k] = z;
    }
  }
}

// staticvec[b][k][h] = sum_s P0[b][k][s]*hbf[b][s][h]
__global__ void __launch_bounds__(512) k_statvec(const float* __restrict__ P0,
                                                 const ushort* __restrict__ hbf,
                                                 const int* __restrict__ lengths,
                                                 float* __restrict__ statvec) {
  __shared__ float P[4 * 512];
  __shared__ float red2[8 * 256];
  int bid = blockIdx.x, tid = threadIdx.x;
  int b = bid >> 3, hs = bid & 7;
#pragma unroll
  for (int k = 0; k < 4; k++) P[k * 512 + tid] = P0[((size_t)b * 4 + k) * 512 + tid];
  __syncthreads();
  int h = tid & 63, w8 = tid >> 6;
  int len = lengths[b];
  float a0 = 0.f, a1 = 0.f, a2 = 0.f, a3 = 0.f;
  for (int si = len + ((w8 - len) & 7); si < 512; si += 8) {
    float hv = bf2f(hbf[((size_t)(b * 512 + si) * 512) + (hs << 6) + h]);
    a0 += P[si] * hv;
    a1 += P[512 + si] * hv;
    a2 += P[1024 + si] * hv;
    a3 += P[1536 + si] * hv;
  }
  red2[(w8 << 8) + h] = a0;
  red2[(w8 << 8) + 64 + h] = a1;
  red2[(w8 << 8) + 128 + h] = a2;
  red2[(w8 << 8) + 192 + h] = a3;
  __syncthreads();
  if (tid < 256) {
    int k = tid >> 6, hh = tid & 63;
    float acc = 0.f;
#pragma unroll
    for (int c = 0; c < 8; c++) acc += red2[(c << 8) + (k << 6) + hh];
    statvec[((size_t)b * 4 + k) * 512 + (hs << 6) + hh] = acc;
  }
}

// ---------------- setup GEMM: gi0[m][j] = inb[m] . Wih0[j][0:512] ------------
__global__ void __launch_bounds__(256) k_gin0(const ushort* __restrict__ Wg0b,
                                              const ushort* __restrict__ inb,
                                              float* __restrict__ gi0) {
  __shared__ float red[4 * 528];
  int tid = threadIdx.x, w = tid >> 6;
  int j0 = blockIdx.x * 16;
  for (int mt = 0; mt < 4; mt++) {
    int m0 = (blockIdx.y * 4 + mt) * 32;
    mfma_slice(Wg0b, 3072, j0, 4, inb + (size_t)m0 * 512, 512, 1 << 30,
               inb + (size_t)m0 * 512, 512, 0, w * 128, w * 128 + 128,
               red + w * 528);
    __syncthreads();
#pragma unroll
    for (int e = 0; e < 2; e++) {
      int idx = tid + e * 256;
      int j = idx >> 5, b = idx & 31;
      float v = 0.f;
#pragma unroll
      for (int ww = 0; ww < 4; ww++) v += red[ww * 528 + j * 33 + b];
      gi0[(size_t)(m0 + b) * 2048 + j0 + j] = v;
    }
    __syncthreads();
  }
}

// ---------------- K1: o1(t-1) || [q+scores](t) -------------------------------
__global__ void __launch_bounds__(512) k_scq(
    const ushort* __restrict__ Wq, const ushort* __restrict__ Wo1,
    const ushort* __restrict__ h1cur, const ushort* __restrict__ xb,
    const float* __restrict__ bo1, ushort* __restrict__ o1bf,
    const ushort* __restrict__ hpb, const float* __restrict__ ba1,
    const float* __restrict__ Wa2, const int* __restrict__ lengths,
    float4* __restrict__ scoresP4, int t) {
  __shared__ float red[8 * 528];
  __shared__ float qs[64], wa2s[256], ba1s[64];
  int bid = blockIdx.x, tid = threadIdx.x, w = tid >> 6, lane = tid & 63;
  if (bid < 32) {
    if (t < 1) return;
    mfma_slice(Wo1, 2560, bid * 16, 4, h1cur, 512, 512, xb, 2048, 512,
               w * 320, w * 320 + 320, red + w * 528);
    __syncthreads();
    int j = tid & 15, b = tid >> 4;
    float v = 0.f;
#pragma unroll
    for (int ww = 0; ww < 8; ww++) v += red[ww * 528 + j * 33 + b];
    int jj = bid * 16 + j;
    o1bf[b * 512 + jj] = f2bf(fmaxf(v + bo1[jj], 0.f));
  } else {
    if (t >= 64) return;
    int r = bid - 32;  // 0..255
    int b = r >> 3, kdq = r & 7, kd0 = kdq << 6;
    if (tid < 256) wa2s[tid] = Wa2[(tid >> 6) * 512 + kd0 + (tid & 63)];
    else if (tid < 320) ba1s[tid - 256] = ba1[kd0 + (tid - 256)];
    // q phase: wave w computes q rows kd0+w*8 .. +8
    {
      bf16x8 hv8 = *(const bf16x8*)(h1cur + b * 512 + lane * 8);
      float hf[8];
#pragma unroll
      for (int e2 = 0; e2 < 8; e2++) hf[e2] = bf2f(((ushort*)&hv8)[e2]);
#pragma unroll
      for (int rr = 0; rr < 8; rr++) {
        int row = kd0 + w * 8 + rr;
        bf16x8 wv8 = *(const bf16x8*)(Wq + (size_t)row * 512 + lane * 8);
        float acc = 0.f;
#pragma unroll
        for (int e2 = 0; e2 < 8; e2++) acc += hf[e2] * bf2f(((ushort*)&wv8)[e2]);
        acc = wave_sum(acc);
        if (lane == 0) qs[w * 8 + rr] = acc;
      }
    }
    __syncthreads();
    int s = tid, len = lengths[b];
    if ((tid & ~63) >= len) return;  // whole wave static -> skip
    float m = (s < len) ? 1.f : 0.f;
    float a0 = 0.f, a1 = 0.f, a2 = 0.f, a3 = 0.f;
    const ushort* hpr = hpb + (size_t)(b * 512 + s) * 512 + kd0;
#pragma unroll
    for (int i8 = 0; i8 < 8; i8++) {
      bf16x8 hv8 = *(const bf16x8*)(hpr + i8 * 8);
#pragma unroll
      for (int e = 0; e < 8; e++) {
        int i = i8 * 8 + e;
        float a = fmaxf(bf2f(((ushort*)&hv8)[e]) + ba1s[i] + m * qs[i], 0.f);
        a0 += wa2s[i] * a;
        a1 += wa2s[64 + i] * a;
        a2 += wa2s[128 + i] * a;
        a3 += wa2s[192 + i] * a;
      }
    }
    scoresP4[((size_t)(kdq * 32 + b)) * 512 + s] = make_float4(a0, a1, a2, a3);
  }
}

// ---------------- K2: out(t-1) || ctx(t) -------------------------------------
__global__ void __launch_bounds__(512) k_ctxout(
    const float4* __restrict__ scoresP4, const float* __restrict__ ba2,
    const int* __restrict__ lengths, const ushort* __restrict__ hbf,
    const float* __restrict__ m0v, const float* __restrict__ statZ,
    const float* __restrict__ statvec, ushort* __restrict__ xb,
    const ushort* __restrict__ Wo2, const ushort* __restrict__ o1bf,
    const float* __restrict__ bo2, float* __restrict__ outp, int t) {
  __shared__ float red[8 * 528];
  __shared__ float P[4 * 512];
  __shared__ float red2[8 * 256];
  __shared__ float st[32], st2[32];
  int bid = blockIdx.x, tid = threadIdx.x;
  if (bid < 32) {
    if (t < 1) return;
    int w = tid >> 6;
    mfma_slice(Wo2, 512, bid * 16, 4, o1bf, 512, 1 << 30, o1bf, 512, 0,
               w * 64, w * 64 + 64, red + w * 528);
    __syncthreads();
    int j = tid & 15, b = tid >> 4;
    float v = 0.f;
#pragma unroll
    for (int ww = 0; ww < 8; ww++) v += red[ww * 528 + j * 33 + b];
    int jj = bid * 16 + j;
    outp[((size_t)b * 64 + (t - 1)) * 512 + jj] = tanhf(v + bo2[jj]);
  } else {
    if (t >= 64) return;
    int r = bid - 32;
    int b = r >> 3, hs = r & 7;
    int lane = tid & 63, w = tid >> 6;
    int s = tid, len = lengths[b];
    bool act = s < len;
    float v[4];
    {
      float a0 = ba2[0], a1 = ba2[1], a2 = ba2[2], a3 = ba2[3];
      if (act) {
#pragma unroll
        for (int q = 0; q < 8; q++) {
          float4 p = scoresP4[((size_t)(q * 32 + b)) * 512 + s];
          a0 += p.x; a1 += p.y; a2 += p.z; a3 += p.w;
        }
        v[0] = fmaxf(a0, 0.f); v[1] = fmaxf(a1, 0.f);
        v[2] = fmaxf(a2, 0.f); v[3] = fmaxf(a3, 0.f);
      } else {
        v[0] = v[1] = v[2] = v[3] = -1e30f;
      }
    }
    float M[4];
#pragma unroll
    for (int k = 0; k < 4; k++) {
      float mk = wave_max(v[k]);
      if (lane == 0) st[w * 4 + k] = mk;
    }
    __syncthreads();
#pragma unroll
    for (int k = 0; k < 4; k++) {
      float m = st[k];
#pragma unroll
      for (int w2 = 1; w2 < 8; w2++) m = fmaxf(m, st[w2 * 4 + k]);
      M[k] = fmaxf(m, m0v[b * 4 + k]);
    }
    float e[4];
#pragma unroll
    for (int k = 0; k < 4; k++) {
      e[k] = act ? __expf(v[k] - M[k]) : 0.f;
      float sk = wave_sum(e[k]);
      if (lane == 0) st2[w * 4 + k] = sk;
    }
    __syncthreads();
    float sc[4];
#pragma unroll
    for (int k = 0; k < 4; k++) {
      float dynZ = 0.f;
#pragma unroll
      for (int w2 = 0; w2 < 8; w2++) dynZ += st2[w2 * 4 + k];
      float scB = __expf(m0v[b * 4 + k] - M[k]);
      float Z = dynZ + scB * statZ[b * 4 + k];
      float invZ = 1.f / Z;
      P[k * 512 + s] = e[k] * invZ;
      sc[k] = scB * invZ;
    }
    __syncthreads();
    int h = tid & 63, w8 = tid >> 6;
    float a0 = 0.f, a1 = 0.f, a2 = 0.f, a3 = 0.f;
    const ushort* hb0 = hbf + ((size_t)b * 512) * 512 + (hs << 6) + h;
    int si = w8;
    for (; si + 24 < len; si += 32) {
      float h0v = bf2f(hb0[(size_t)si * 512]);
      float h1v = bf2f(hb0[(size_t)(si + 8) * 512]);
      float h2v = bf2f(hb0[(size_t)(si + 16) * 512]);
      float h3v = bf2f(hb0[(size_t)(si + 24) * 512]);
      a0 += P[si] * h0v + P[si + 8] * h1v + P[si + 16] * h2v + P[si + 24] * h3v;
      a1 += P[512 + si] * h0v + P[512 + si + 8] * h1v + P[512 + si + 16] * h2v +
            P[512 + si + 24] * h3v;
      a2 += P[1024 + si] * h0v + P[1024 + si + 8] * h1v + P[1024 + si + 16] * h2v +
            P[1024 + si + 24] * h3v;
      a3 += P[1536 + si] * h0v + P[1536 + si + 8] * h1v + P[1536 + si + 16] * h2v +
            P[1536 + si + 24] * h3v;
    }
    for (; si < len; si += 8) {
      float hv = bf2f(hb0[(size_t)si * 512]);
      a0 += P[si] * hv;
      a1 += P[512 + si] * hv;
      a2 += P[1024 + si] * hv;
      a3 += P[1536 + si] * hv;
    }
    red2[(w8 << 8) + h] = a0;
    red2[(w8 << 8) + 64 + h] = a1;
    red2[(w8 << 8) + 128 + h] = a2;
    red2[(w8 << 8) + 192 + h] = a3;
    __syncthreads();
    if (tid < 256) {
      int k = tid >> 6, hh = tid & 63;
      float acc = 0.f;
#pragma unroll
      for (int c = 0; c < 8; c++) acc += red2[(c << 8) + (k << 6) + hh];
      acc += sc[k] * statvec[((size_t)b * 4 + k) * 512 + (hs << 6) + hh];
      xb[b * 2048 + (k << 9) + (hs << 6) + hh] = f2bf(acc);
    }
  }
}

// ---------------- K3: LSTM cell0 (512 thr, 8-way k-split, K=2560) ------------
__global__ void __launch_bounds__(512) k_cell0(
    const ushort* __restrict__ Wg0b, const ushort* __restrict__ xb,
    const ushort* __restrict__ h0cur, const float* __restrict__ gi0,
    const float* __restrict__ bih, const float* __restrict__ bhh,
    float* __restrict__ cst, ushort* __restrict__ hnew, int t) {
  __shared__ float red[8 * 528];
  int bid = blockIdx.x, tid = threadIdx.x, w = tid >> 6;
  mfma_slice(Wg0b + 512, 3072, bid * 4, 512, xb, 2048, 2048, h0cur, 512, 2048,
             w * 320, w * 320 + 320, red + w * 528);
  __syncthreads();
  if (tid < 128) {
    int b = tid & 31, dh = tid >> 5;
    int h = bid * 4 + dh;
    float G[4];
#pragma unroll
    for (int g = 0; g < 4; g++) {
      float v = bih[g * 512 + h] + bhh[g * 512 + h] +
                gi0[(size_t)(t * 32 + b) * 2048 + g * 512 + h];
#pragma unroll
      for (int ww = 0; ww < 8; ww++) v += red[ww * 528 + (g * 4 + dh) * 33 + b];
      G[g] = v;
    }
    float i_ = sigmoidf_(G[0]), f_ = sigmoidf_(G[1]);
    float gg = tanhf(G[2]), o_ = sigmoidf_(G[3]);
    float cn = f_ * cst[b * 512 + h] + i_ * gg;
    cst[b * 512 + h] = cn;
    hnew[b * 512 + h] = f2bf(o_ * tanhf(cn));
  }
}

// ---------------- K4: LSTM cell1 (512 thr, 8-way k-split, K=1024) ------------
__global__ void __launch_bounds__(512) k_cell1(
    const ushort* __restrict__ Wg1b, const ushort* __restrict__ h0new,
    const ushort* __restrict__ h1cur, const float* __restrict__ bih,
    const float* __restrict__ bhh, float* __restrict__ cst,
    ushort* __restrict__ hnew) {
  __shared__ float red[8 * 528];
  int bid = blockIdx.x, tid = threadIdx.x, w = tid >> 6;
  mfma_slice(Wg1b, 1024, bid * 4, 512, h0new, 512, 512, h1cur, 512, 512,
             w * 128, w * 128 + 128, red + w * 528);
  __syncthreads();
  if (tid < 128) {
    int b = tid & 31, dh = tid >> 5;
    int h = bid * 4 + dh;
    float G[4];
#pragma unroll
    for (int g = 0; g < 4; g++) {
      float v = bih[g * 512 + h] + bhh[g * 512 + h];
#pragma unroll
      for (int ww = 0; ww < 8; ww++) v += red[ww * 528 + (g * 4 + dh) * 33 + b];
      G[g] = v;
    }
    float i_ = sigmoidf_(G[0]), f_ = sigmoidf_(G[1]);
    float gg = tanhf(G[2]), o_ = sigmoidf_(G[3]);
    float cn = f_ * cst[b * 512 + h] + i_ * gg;
    cst[b * 512 + h] = cn;
    hnew[b * 512 + h] = f2bf(o_ * tanhf(cn));
  }
}

// ---------------- host -------------------------------------------------------
extern "C" void kernel_launch(void* const* d_in, const int* in_sizes, int n_in,
                              void* d_out, int out_size, void* d_ws, size_t ws_size,
                              hipStream_t stream) {
  const float* inputs  = (const float*)d_in[0];
  const int*   lengths = (const int*)d_in[1];
  const float* fh      = (const float*)d_in[2];
  const float* hiddens = (const float*)d_in[3];
  const float* Wa1  = (const float*)d_in[6];
  const float* ba1  = (const float*)d_in[7];
  const float* Wa2  = (const float*)d_in[8];
  const float* ba2  = (const float*)d_in[9];
  const float* Wih0 = (const float*)d_in[10];
  const float* Whh0 = (const float*)d_in[11];
  const float* bih0 = (const float*)d_in[12];
  const float* bhh0 = (const float*)d_in[13];
  const float* Wih1 = (const float*)d_in[14];
  const float* Whh1 = (const float*)d_in[15];
  const float* bih1 = (const float*)d_in[16];
  const float* bhh1 = (const float*)d_in[17];
  const float* Wo1  = (const float*)d_in[18];
  const float* bo1  = (const float*)d_in[19];
  const float* Wo2  = (const float*)d_in[20];
  const float* bo2  = (const float*)d_in[21];
  float* outp = (float*)d_out;

  char* p = (char*)d_ws;
  ushort* hpb = (ushort*)p; p += (size_t)32 * 512 * 512 * 2;
  ushort* hbf = (ushort*)p; p += (size_t)32 * 512 * 512 * 2;
  float4* scoresP4 = (float4*)p; p += (size_t)8 * 32 * 512 * 16;
  float* scores0 = (float*)p; p += (size_t)32 * 4 * 512 * 4;
  float* P0      = (float*)p; p += (size_t)32 * 4 * 512 * 4;
  float* statvec = (float*)p; p += (size_t)32 * 4 * 512 * 4;
  float* m0v     = (float*)p; p += 128 * sizeof(float);
  float* statZ   = (float*)p; p += 128 * sizeof(float);
  ushort* xb     = (ushort*)p; p += (size_t)32 * 2048 * 2;
  ushort* h0b    = (ushort*)p; p += (size_t)2 * 32 * 512 * 2;
  ushort* h1b    = (ushort*)p; p += (size_t)2 * 32 * 512 * 2;
  ushort* o1bf   = (ushort*)p; p += (size_t)32 * 512 * 2;
  float* c0      = (float*)p; p += (size_t)32 * 512 * 4;
  float* c1      = (float*)p; p += (size_t)32 * 512 * 4;
  ushort* Wg0b   = (ushort*)p; p += (size_t)2048 * 3072 * 2;
  ushort* Wg1b   = (ushort*)p; p += (size_t)2048 * 1024 * 2;
  ushort* Wo1b   = (ushort*)p; p += (size_t)512 * 2560 * 2;
  ushort* Wo2b   = (ushort*)p; p += (size_t)512 * 512 * 2;
  ushort* Wqb    = (ushort*)p; p += (size_t)512 * 512 * 2;
  ushort* Wa1c   = (ushort*)p; p += (size_t)512 * 512 * 2;
  ushort* inb    = (ushort*)p; p += (size_t)2048 * 512 * 2;
  float* gi0     = (float*)p; p += (size_t)2048 * 2048 * 4;

  k_init<<<64, 256, 0, stream>>>(fh, h0b, h1b, c0, c1);
  k_prep<<<4096, 256, 0, stream>>>(hiddens, hbf);
  k_inprep<<<1024, 256, 0, stream>>>(inputs, inb);
  k_wcvt<<<6144, 256, 0, stream>>>(Wih0, 2560, Whh0, 512, 2560, 3072, Wg0b);
  k_wcvt<<<2048, 256, 0, stream>>>(Wih1, 512, Whh1, 512, 512, 1024, Wg1b);
  k_wcvt<<<1280, 256, 0, stream>>>(Wo1, 2560, Wo1, 2560, 2560, 2560, Wo1b);
  k_wcvt<<<256, 256, 0, stream>>>(Wo2, 512, Wo2, 512, 512, 512, Wo2b);
  k_wcvt<<<256, 256, 0, stream>>>(Wa1, 1024, Wa1, 1024, 512, 512, Wqb);
  k_wcvt<<<256, 256, 0, stream>>>(Wa1 + 512, 1024, Wa1 + 512, 1024, 1 << 30, 512, Wa1c);
  k_hidproj2<<<dim3(32, 128), 256, 0, stream>>>(Wa1c, hbf, hpb);
  k_gin0<<<dim3(128, 16), 256, 0, stream>>>(Wg0b, inb, gi0);
  k_scst<<<256, 512, 0, stream>>>(hpb, ba1, Wa2, scoresP4);
  k_sum0<<<32, 512, 0, stream>>>(scoresP4, ba2, scores0);
  k_stat0<<<32, 512, 0, stream>>>(scores0, lengths, m0v, statZ, P0);
  k_statvec<<<256, 512, 0, stream>>>(P0, hbf, lengths, statvec);

  for (int t = 0; t <= 64; t++) {
    const ushort* h1cur = h1b + (size_t)(t & 1) * 16384;
    const ushort* h0cur = h0b + (size_t)(t & 1) * 16384;
    ushort* h0nxt = h0b + (size_t)((t + 1) & 1) * 16384;
    ushort* h1nxt = h1b + (size_t)((t + 1) & 1) * 16384;
    k_scq<<<288, 512, 0, stream>>>(Wqb, Wo1b, h1cur, xb, bo1, o1bf, hpb, ba1,
                                   Wa2, lengths, scoresP4, t);
    k_ctxout<<<288, 512, 0, stream>>>(scoresP4, ba2, lengths, hbf, m0v, statZ,
                                      statvec, xb, Wo2b, o1bf, bo2, outp, t);
    if (t < 64) {
      k_cell0<<<128, 512, 0, stream>>>(Wg0b, xb, h0cur, gi0, bih0, bhh0, c0,
                                       h0nxt, t);
      k_cell1<<<128, 512, 0, stream>>>(Wg1b, h0nxt, h1cur, bih1, bhh1, c1, h1nxt);
    }
  }
}